// Round 8
// baseline (336.425 us; speedup 1.0000x reference)
//
#include <hip/hip_runtime.h>

// ClassicalSelfAttention: B=1, N=4096, D=768, H=12, Hd=64, fp32 in/out.
// R8 = R7 with the split-coverage fix: ntiles = 64/S (N_TOK/64 tiles total), so
// S splits cover ALL 64 KV tiles (R7 passed 32/S and attended only half the keys).
// KV-split-4 (ws-size checked), grid 768 = 3 blocks/CU; GEMMs use m97-style
// global_load_lds width-16 staging. Attention math unchanged (sigma-staged K,
// exp2-domain Q, ones-MFMA l, 2-deep named-scalar prefetch, lgkm-only barriers).

typedef __attribute__((ext_vector_type(8))) short short8;   // 8 x bf16 fragment
typedef __attribute__((ext_vector_type(4))) float f32x4;    // MFMA accumulator

#define N_TOK 4096
#define NHEAD 12
#define DMODEL 768
#define QK_LD 1536
#define KSTR 68          // attn LDS row stride (ushorts)

#if defined(__has_builtin)
#if __has_builtin(__builtin_amdgcn_exp2f)
#define EXP2F __builtin_amdgcn_exp2f
#else
#define EXP2F exp2f
#endif
#else
#define EXP2F exp2f
#endif

#if defined(__has_builtin)
#if __has_builtin(__builtin_amdgcn_perm)
#define PACK2BF(hi, lo) __builtin_amdgcn_perm((hi), (lo), 0x07060302u)
#else
#define PACK2BF(hi, lo) ((((hi)) & 0xffff0000u) | (((lo)) >> 16))
#endif
#else
#define PACK2BF(hi, lo) ((((hi)) & 0xffff0000u) | (((lo)) >> 16))
#endif

__device__ __forceinline__ ushort bf16bits(float x) {
  union { float f; unsigned u; } cv; cv.f = x;
  unsigned u = cv.u;
  u += 0x7fffu + ((u >> 16) & 1u);   // RNE
  return (ushort)(u >> 16);
}
__device__ __forceinline__ float bf2f(ushort u) {
  return __uint_as_float(((unsigned)u) << 16);
}

// async global->LDS, 16 B per lane; lds base must be wave-uniform, HW scatters lane*16.
__device__ __forceinline__ void async16(ushort* lds, const ushort* g) {
  __builtin_amdgcn_global_load_lds((const __attribute__((address_space(1))) unsigned int*)g,
                                   (__attribute__((address_space(3))) unsigned int*)lds,
                                   16, 0, 0);
}

// ---- fused fp32->bf16 converts for x (3072 blk), w_qkv (1728 blk), w_out (576 blk) ----
__global__ void __launch_bounds__(256) cvt3(const float* __restrict__ x,
                                            const float* __restrict__ wq,
                                            const float* __restrict__ wo,
                                            ushort* __restrict__ xb,
                                            ushort* __restrict__ wqb,
                                            ushort* __restrict__ wob) {
  const int b = blockIdx.x, t = threadIdx.x;
  const float* src; ushort* dst; int i;
  if (b < 3072)      { src = x;  dst = xb;  i = b * 256 + t; }           // 786432 f4
  else if (b < 4800) { src = wq; dst = wqb; i = (b - 3072) * 256 + t; }  // 442368 f4
  else               { src = wo; dst = wob; i = (b - 4800) * 256 + t; }  // 147456 f4
  const float4 v = ((const float4*)src)[i];
  ushort4 o;
  o.x = bf16bits(v.x); o.y = bf16bits(v.y); o.z = bf16bits(v.z); o.w = bf16bits(v.w);
  ((ushort4*)dst)[i] = o;
}

// m97-style staging of a 128x64 bf16 tile: wave w stages rows w*32..+31 via 4
// async16 (each = 8 rows x 64 cols contiguous LDS). LDS unpadded [row][64].
#define GEMM_STAGE(Ms, Mp, MK)                                                 \
  do {                                                                         \
    _Pragma("unroll")                                                          \
    for (int i_ = 0; i_ < 4; i_++)                                             \
      async16(&Ms[(wave * 32 + i_ * 8) * 64],                                  \
              Mp + (size_t)(wave * 32 + i_ * 8 + lrow) * (MK) + lcol);         \
  } while (0)

// ---- GEMM1: qkv = x @ w_qkv^T.  Q cols pre-scaled by log2e/8 -> qk[n][1536];
//      V cols -> vtg[h*64+d][n] (fused transpose).
__global__ void __launch_bounds__(256) gemm_qkv(const ushort* __restrict__ A,
                                                const ushort* __restrict__ B,
                                                ushort* __restrict__ qkb,
                                                ushort* __restrict__ vtg) {
  __shared__ __align__(16) ushort As[128 * 64];
  __shared__ __align__(16) ushort Bs[128 * 64];
  const int tid = threadIdx.x;
  const int wave = tid >> 6, lane = tid & 63, quad = lane >> 4, l16 = lane & 15;
  const int wm = wave & 1, wn = wave >> 1;
  const int lrow = lane >> 3, lcol = (lane & 7) * 8;
  const int m0 = blockIdx.y * 128, n0 = blockIdx.x * 128;
  const int K = DMODEL;

  f32x4 acc[4][4] = {};
  const ushort* Ap = A + (size_t)m0 * K;
  const ushort* Bp = B + (size_t)n0 * K;

  for (int k0 = 0; k0 < K; k0 += 64) {
    GEMM_STAGE(As, Ap + k0, K);
    GEMM_STAGE(Bs, Bp + k0, K);
    __syncthreads();   // drains vmcnt -> staged data visible
#pragma unroll
    for (int ks = 0; ks < 2; ks++) {
      short8 af[4], bf[4];
#pragma unroll
      for (int i = 0; i < 4; i++) {
        af[i] = *(const short8*)&As[(wm * 64 + i * 16 + l16) * 64 + ks * 32 + quad * 8];
        bf[i] = *(const short8*)&Bs[(wn * 64 + i * 16 + l16) * 64 + ks * 32 + quad * 8];
      }
#pragma unroll
      for (int mi = 0; mi < 4; mi++)
#pragma unroll
        for (int ni = 0; ni < 4; ni++)
          acc[mi][ni] = __builtin_amdgcn_mfma_f32_16x16x32_bf16(af[mi], bf[ni], acc[mi][ni], 0, 0, 0);
    }
    __syncthreads();
  }

  if (n0 < QK_LD) {
    // Q/K epilogue: qk[row][col].  Q (col<768) pre-scaled so attn exp2 needs no mul.
    const float qsc = (n0 + 128 <= 768) ? 0.18033688011112042f : 1.0f;  // log2(e)/8
#pragma unroll
    for (int mi = 0; mi < 4; mi++)
#pragma unroll
      for (int ni = 0; ni < 4; ni++) {
        const int col = n0 + wn * 64 + ni * 16 + l16;
#pragma unroll
        for (int rr = 0; rr < 4; rr++) {
          const int row = m0 + wm * 64 + mi * 16 + quad * 4 + rr;
          qkb[(size_t)row * QK_LD + col] = bf16bits(acc[mi][ni][rr] * qsc);
        }
      }
  } else {
    // V epilogue: vtg[col-1536][row], 4 consecutive rows packed per lane.
#pragma unroll
    for (int mi = 0; mi < 4; mi++)
#pragma unroll
      for (int ni = 0; ni < 4; ni++) {
        const int col = n0 + wn * 64 + ni * 16 + l16 - QK_LD;   // = h*64+d
        const int rowb = m0 + wm * 64 + mi * 16 + quad * 4;
        const unsigned u0 = (unsigned)bf16bits(acc[mi][ni][0]) |
                            ((unsigned)bf16bits(acc[mi][ni][1]) << 16);
        const unsigned u1 = (unsigned)bf16bits(acc[mi][ni][2]) |
                            ((unsigned)bf16bits(acc[mi][ni][3]) << 16);
        *(uint2*)&vtg[(size_t)col * N_TOK + rowb] = make_uint2(u0, u1);
      }
  }
}

// ---- GEMM2: out = aout @ w_out^T + bias (fp32 out) ----
__global__ void __launch_bounds__(256) gemm_out(const ushort* __restrict__ A,
                                                const ushort* __restrict__ B,
                                                float* __restrict__ Cf,
                                                const float* __restrict__ bias) {
  __shared__ __align__(16) ushort As[128 * 64];
  __shared__ __align__(16) ushort Bs[128 * 64];
  const int tid = threadIdx.x;
  const int wave = tid >> 6, lane = tid & 63, quad = lane >> 4, l16 = lane & 15;
  const int wm = wave & 1, wn = wave >> 1;
  const int lrow = lane >> 3, lcol = (lane & 7) * 8;
  const int m0 = blockIdx.y * 128, n0 = blockIdx.x * 128;
  const int K = DMODEL, Nn = DMODEL;

  f32x4 acc[4][4] = {};
  const ushort* Ap = A + (size_t)m0 * K;
  const ushort* Bp = B + (size_t)n0 * K;

  for (int k0 = 0; k0 < K; k0 += 64) {
    GEMM_STAGE(As, Ap + k0, K);
    GEMM_STAGE(Bs, Bp + k0, K);
    __syncthreads();
#pragma unroll
    for (int ks = 0; ks < 2; ks++) {
      short8 af[4], bf[4];
#pragma unroll
      for (int i = 0; i < 4; i++) {
        af[i] = *(const short8*)&As[(wm * 64 + i * 16 + l16) * 64 + ks * 32 + quad * 8];
        bf[i] = *(const short8*)&Bs[(wn * 64 + i * 16 + l16) * 64 + ks * 32 + quad * 8];
      }
#pragma unroll
      for (int mi = 0; mi < 4; mi++)
#pragma unroll
        for (int ni = 0; ni < 4; ni++)
          acc[mi][ni] = __builtin_amdgcn_mfma_f32_16x16x32_bf16(af[mi], bf[ni], acc[mi][ni], 0, 0, 0);
    }
    __syncthreads();
  }

#pragma unroll
  for (int mi = 0; mi < 4; mi++)
#pragma unroll
    for (int ni = 0; ni < 4; ni++) {
      const int col = n0 + wn * 64 + ni * 16 + l16;
#pragma unroll
      for (int rr = 0; rr < 4; rr++) {
        const int row = m0 + wm * 64 + mi * 16 + quad * 4 + rr;
        Cf[(size_t)row * Nn + col] = acc[mi][ni][rr] + bias[col];
      }
    }
}

// ---- Flash attention: q=256/block, transposed-S, static max, KV-split-S ----
// Grid 192*S (1D). XCD swizzle: s8=b%8, slice=s8+8*(j%nsl8), qb=j/nsl8;
// h=slice%12, sp=slice/12. Each XCD serves nsl8 slices (L2-resident K/V).
// ntiles = 64/S (N_TOK/64 total tiles split across S).
#define BARRIER_LGKM() asm volatile("s_waitcnt lgkmcnt(0)\n\ts_barrier" ::: "memory")

#define ATTN_LOAD(tile, K0, K1, V0, V1)                                        \
  do {                                                                         \
    const int kv0_ = (tile) * 64;                                              \
    K0 = *(const uint4*)(kbase + (size_t)(kv0_ + sr) * QK_LD);                 \
    K1 = *(const uint4*)(kbase + (size_t)(kv0_ + sr + 32) * QK_LD);            \
    V0 = *(const uint4*)(vbase + (size_t)sr * N_TOK + kv0_ + sc);              \
    V1 = *(const uint4*)(vbase + (size_t)(sr + 32) * N_TOK + kv0_ + sc);       \
  } while (0)

#define ATTN_SINK(buf, K0, K1, V0, V1)                                         \
  do {                                                                         \
    *(uint4*)&Ks[buf][sg * KSTR + sc] = K0;                                    \
    *(uint4*)&Ks[buf][(sg + 32) * KSTR + sc] = K1;                             \
    *(uint4*)&Vs[buf][sr * KSTR + sc] = V0;                                    \
    *(uint4*)&Vs[buf][(sr + 32) * KSTR + sc] = V1;                             \
  } while (0)

#define ATTN_TILE(KbP, VbP)                                                    \
  do {                                                                         \
    const ushort* Kb_ = (KbP);                                                 \
    const ushort* Vb_ = (VbP);                                                 \
    f32x4 st[4][4];                                                            \
    _Pragma("unroll")                                                          \
    for (int nt = 0; nt < 4; nt++) {                                           \
      const short8 kf0 = *(const short8*)&Kb_[(nt * 16 + l16) * KSTR + quad * 8];      \
      const short8 kf1 = *(const short8*)&Kb_[(nt * 16 + l16) * KSTR + 32 + quad * 8]; \
      _Pragma("unroll")                                                        \
      for (int s = 0; s < 4; s++) {                                            \
        f32x4 a = {};                                                          \
        a = __builtin_amdgcn_mfma_f32_16x16x32_bf16(kf0, qf[s][0], a, 0, 0, 0);\
        a = __builtin_amdgcn_mfma_f32_16x16x32_bf16(kf1, qf[s][1], a, 0, 0, 0);\
        st[s][nt] = a;                                                         \
      }                                                                        \
    }                                                                          \
    unsigned pk[4][4][2];                                                      \
    _Pragma("unroll")                                                          \
    for (int s = 0; s < 4; s++)                                                \
      _Pragma("unroll")                                                        \
      for (int nt = 0; nt < 4; nt++) {                                         \
        const unsigned u0 = __float_as_uint(EXP2F(st[s][nt][0]));              \
        const unsigned u1 = __float_as_uint(EXP2F(st[s][nt][1]));              \
        const unsigned u2 = __float_as_uint(EXP2F(st[s][nt][2]));              \
        const unsigned u3 = __float_as_uint(EXP2F(st[s][nt][3]));              \
        pk[s][nt][0] = PACK2BF(u1, u0);                                        \
        pk[s][nt][1] = PACK2BF(u3, u2);                                        \
      }                                                                        \
    _Pragma("unroll")                                                          \
    for (int ks = 0; ks < 2; ks++) {                                           \
      short8 pf[4];                                                            \
      _Pragma("unroll")                                                        \
      for (int s = 0; s < 4; s++) {                                            \
        union { unsigned u[4]; short8 v; } t;                                  \
        t.u[0] = pk[s][2 * ks][0];                                             \
        t.u[1] = pk[s][2 * ks][1];                                             \
        t.u[2] = pk[s][2 * ks + 1][0];                                         \
        t.u[3] = pk[s][2 * ks + 1][1];                                         \
        pf[s] = t.v;                                                           \
        lacc[s] = __builtin_amdgcn_mfma_f32_16x16x32_bf16(pf[s], onesf, lacc[s], 0, 0, 0); \
      }                                                                        \
      _Pragma("unroll")                                                        \
      for (int dt = 0; dt < 4; dt++) {                                         \
        const short8 vf = *(const short8*)&Vb_[(dt * 16 + l16) * KSTR + ks * 32 + quad * 8]; \
        _Pragma("unroll")                                                      \
        for (int s = 0; s < 4; s++)                                            \
          o[s][dt] = __builtin_amdgcn_mfma_f32_16x16x32_bf16(pf[s], vf, o[s][dt], 0, 0, 0); \
      }                                                                        \
    }                                                                          \
  } while (0)

__global__ void __launch_bounds__(256, 3) attn_flash(const ushort* __restrict__ qk,
                                                     const ushort* __restrict__ vtg,
                                                     ushort* __restrict__ pob,
                                                     float* __restrict__ pl,
                                                     int ntiles, int nsl8) {
  __shared__ __align__(16) ushort Ks[2][64 * KSTR];
  __shared__ __align__(16) ushort Vs[2][64 * KSTR];

  const int b = blockIdx.x;
  const int s8 = b & 7;               // presumed XCD (round-robin dispatch)
  const int j = b >> 3;
  const int slice = s8 + 8 * (j % nsl8);   // 0..12*S-1, pinned to XCD s8
  const int qb = j / nsl8;                 // 0..15
  const int h = slice % NHEAD;
  const int sp = slice / NHEAD;            // 0..S-1

  const int tid = threadIdx.x;
  const int wave = tid >> 6, lane = tid & 63, quad = lane >> 4, l16 = lane & 15;
  const int q0 = qb * 256;

  // Q fragments (B-operand: q = l16 within strip, k = quad*8+j). Pre-scaled by log2e/8.
  short8 qf[4][2];
#pragma unroll
  for (int s = 0; s < 4; s++) {
    const ushort* qp = qk + (size_t)(q0 + wave * 64 + s * 16 + l16) * QK_LD + h * 64 + quad * 8;
    qf[s][0] = *(const short8*)qp;
    qf[s][1] = *(const short8*)(qp + 32);
  }

  const int sr = tid >> 3, sc = (tid & 7) * 8;
  // sigma row permutation for K staging: g -> (2*(g>>5)+((g>>2)&1))*16+((g>>3)&3)*4+(g&3)
  const int sg = ((sr >> 2) & 1) * 16 + ((sr >> 3) & 3) * 4 + (sr & 3);

  const ushort* kbase = qk + 768 + h * 64 + sc;
  const ushort* vbase = vtg + (size_t)(h * 64) * N_TOK;
  const int kt0 = sp * ntiles;

  f32x4 o[4][4] = {};
  f32x4 lacc[4] = {};
  const short8 onesf = { (short)0x3F80, (short)0x3F80, (short)0x3F80, (short)0x3F80,
                         (short)0x3F80, (short)0x3F80, (short)0x3F80, (short)0x3F80 };

  uint4 ka0, ka1, va0, va1;   // slot A (odd tiles)
  uint4 kb0, kb1, vb0, vb1;   // slot B (even tiles >= 2)

  // prologue: tile kt0 direct to LDS buf0; prefetch tile kt0+1 into A
  ATTN_LOAD(kt0, ka0, ka1, va0, va1);
  ATTN_SINK(0, ka0, ka1, va0, va1);
  ATTN_LOAD(kt0 + 1, ka0, ka1, va0, va1);

  for (int kt = 0; kt < ntiles; kt += 2) {
    // ---- even tile kt: compute LDS0; sink A(tile kt+1)->LDS1; prefetch B(tile kt+2)
    BARRIER_LGKM();
    if (kt + 2 < ntiles) ATTN_LOAD(kt0 + kt + 2, kb0, kb1, vb0, vb1);
    ATTN_TILE(Ks[0], Vs[0]);
    ATTN_SINK(1, ka0, ka1, va0, va1);
    // ---- odd tile kt+1: compute LDS1; sink B(tile kt+2)->LDS0; prefetch A(tile kt+3)
    BARRIER_LGKM();
    if (kt + 3 < ntiles) ATTN_LOAD(kt0 + kt + 3, ka0, ka1, va0, va1);
    ATTN_TILE(Ks[1], Vs[1]);
    if (kt + 2 < ntiles) ATTN_SINK(0, kb0, kb1, vb0, vb1);
  }

  // ---- epilogue: o and lacc share row indexing (q = s*16 + quad*4 + rr) ----
#pragma unroll
  for (int s = 0; s < 4; s++) {
#pragma unroll
    for (int rr = 0; rr < 4; rr++) {
      const float l = lacc[s][rr];
      const float inv = 1.f / l;
      const int row = q0 + wave * 64 + s * 16 + quad * 4 + rr;
      if (l16 == 0)
        pl[(size_t)(sp * NHEAD + h) * N_TOK + row] = l;
#pragma unroll
      for (int dt = 0; dt < 4; dt++)
        pob[((size_t)sp * N_TOK + row) * DMODEL + h * 64 + dt * 16 + l16] =
            bf16bits(o[s][dt][rr] * inv);
    }
  }
}

// ---- combine S split partials: aout = sum(l_s * o_s) / sum(l_s), bf16 ----
// grid: 786432 ushort4-groups / 256 = 3072 blocks
__global__ void __launch_bounds__(256) combine(const ushort* __restrict__ pob,
                                               const float* __restrict__ pl,
                                               ushort* __restrict__ aout, int S) {
  const int i = blockIdx.x * 256 + threadIdx.x;   // ushort4 index
  const int row = i / (DMODEL / 4);
  const int hd = (i % (DMODEL / 4)) * 4;
  const int h = hd >> 6;
  float lt = 0.f, a0 = 0.f, a1 = 0.f, a2 = 0.f, a3 = 0.f;
  for (int s = 0; s < S; s++) {
    const float l = pl[((size_t)s * NHEAD + h) * N_TOK + row];
    const ushort4 a = *(const ushort4*)&pob[((size_t)s * N_TOK + row) * DMODEL + hd];
    lt += l;
    a0 += l * bf2f(a.x); a1 += l * bf2f(a.y); a2 += l * bf2f(a.z); a3 += l * bf2f(a.w);
  }
  const float inv = 1.f / lt;
  ushort4 r;
  r.x = bf16bits(a0 * inv); r.y = bf16bits(a1 * inv);
  r.z = bf16bits(a2 * inv); r.w = bf16bits(a3 * inv);
  *(ushort4*)&aout[(size_t)row * DMODEL + hd] = r;
}

extern "C" void kernel_launch(void* const* d_in, const int* in_sizes, int n_in,
                              void* d_out, int out_size, void* d_ws, size_t ws_size,
                              hipStream_t stream) {
  const float* x     = (const float*)d_in[0];
  const float* w_qkv = (const float*)d_in[1];
  const float* w_out = (const float*)d_in[2];
  const float* b_out = (const float*)d_in[3];
  float* out = (float*)d_out;

  // ws layout (runtime split count S): pob at 0 (S*6.29 MB; xb/wqkvb alias its
  // head, both dead before attn); then qkb, vtg, woutb, pl. aout aliases qkb.
  const size_t PO_UNIT = 6291456UL;   // 4096*768*2
  const int S = (ws_size >= 4 * PO_UNIT + 20840448UL) ? 4 : 2;
  char* ws = (char*)d_ws;
  ushort* pob   = (ushort*)ws;
  ushort* xb    = (ushort*)ws;                          // [0, 6.29M) dead after gemm1
  ushort* wqkvb = (ushort*)(ws + 6291456UL);            // [6.29M, 9.83M) dead after gemm1
  ushort* qkb   = (ushort*)(ws + (size_t)S * PO_UNIT);
  ushort* vtg   = (ushort*)((char*)qkb + 12582912UL);
  ushort* woutb = (ushort*)((char*)vtg + 6291456UL);
  float*  pl    = (float*)((char*)woutb + 1179648UL);
  ushort* aoutb = qkb;                                  // qkb dead after attn

  // 1) converts (one kernel, 3 ranges: 3072 + 1728 + 576 blocks)
  cvt3<<<5376, 256, 0, stream>>>(x, w_qkv, w_out, xb, wqkvb, woutb);

  // 2) qkv GEMM (global_load_lds staging) with fused V-transpose epilogue + Q pre-scale
  gemm_qkv<<<dim3(18, 32), 256, 0, stream>>>(xb, wqkvb, qkb, vtg);

  // 3) flash attention (q=256/block, KV-split-S over ALL 64 tiles: ntiles = 64/S)
  attn_flash<<<192 * S, 256, 0, stream>>>(qkb, vtg, pob, pl, 64 / S, (12 * S) / 8);

  // 4) combine partials -> aout bf16
  combine<<<3072, 256, 0, stream>>>(pob, pl, aoutb, S);

  // 5) out = aout @ w_out^T + b_out (global_load_lds staging)
  gemm_out<<<dim3(6, 32), 256, 0, stream>>>(aoutb, woutb, out, b_out);
}

// Round 9
// 247.397 us; speedup vs baseline: 1.3599x; 1.3599x over previous
//
#include <hip/hip_runtime.h>

// ClassicalSelfAttention: B=1, N=4096, D=768, H=12, Hd=64, fp32 in/out.
// R9 = R8 with attn __launch_bounds__ reverted to (256,2). R8's (256,3) forced the
// allocator under a ~170-VGPR budget while the wave needs ~205 live regs
// (80 acc + 64 st + 16 qf + 32 prefetch + addr) -> scratch spill, 950 MB/dispatch
// HBM traffic (WRITE_SIZE 612 MB). Bound 2 gives a 256 budget: no spill.
// KV-split-4 over ALL 64 tiles (ntiles=16), grid 768; GEMMs use global_load_lds
// width-16 staging; sigma-staged K, exp2-domain Q, ones-MFMA l, 2-deep named-
// scalar prefetch, lgkm-only barriers.

typedef __attribute__((ext_vector_type(8))) short short8;   // 8 x bf16 fragment
typedef __attribute__((ext_vector_type(4))) float f32x4;    // MFMA accumulator

#define N_TOK 4096
#define NHEAD 12
#define DMODEL 768
#define QK_LD 1536
#define KSTR 68          // attn LDS row stride (ushorts)

#if defined(__has_builtin)
#if __has_builtin(__builtin_amdgcn_exp2f)
#define EXP2F __builtin_amdgcn_exp2f
#else
#define EXP2F exp2f
#endif
#else
#define EXP2F exp2f
#endif

#if defined(__has_builtin)
#if __has_builtin(__builtin_amdgcn_perm)
#define PACK2BF(hi, lo) __builtin_amdgcn_perm((hi), (lo), 0x07060302u)
#else
#define PACK2BF(hi, lo) ((((hi)) & 0xffff0000u) | (((lo)) >> 16))
#endif
#else
#define PACK2BF(hi, lo) ((((hi)) & 0xffff0000u) | (((lo)) >> 16))
#endif

__device__ __forceinline__ ushort bf16bits(float x) {
  union { float f; unsigned u; } cv; cv.f = x;
  unsigned u = cv.u;
  u += 0x7fffu + ((u >> 16) & 1u);   // RNE
  return (ushort)(u >> 16);
}
__device__ __forceinline__ float bf2f(ushort u) {
  return __uint_as_float(((unsigned)u) << 16);
}

// async global->LDS, 16 B per lane; lds base must be wave-uniform, HW scatters lane*16.
__device__ __forceinline__ void async16(ushort* lds, const ushort* g) {
  __builtin_amdgcn_global_load_lds((const __attribute__((address_space(1))) unsigned int*)g,
                                   (__attribute__((address_space(3))) unsigned int*)lds,
                                   16, 0, 0);
}

// ---- fused fp32->bf16 converts for x (3072 blk), w_qkv (1728 blk), w_out (576 blk) ----
__global__ void __launch_bounds__(256) cvt3(const float* __restrict__ x,
                                            const float* __restrict__ wq,
                                            const float* __restrict__ wo,
                                            ushort* __restrict__ xb,
                                            ushort* __restrict__ wqb,
                                            ushort* __restrict__ wob) {
  const int b = blockIdx.x, t = threadIdx.x;
  const float* src; ushort* dst; int i;
  if (b < 3072)      { src = x;  dst = xb;  i = b * 256 + t; }           // 786432 f4
  else if (b < 4800) { src = wq; dst = wqb; i = (b - 3072) * 256 + t; }  // 442368 f4
  else               { src = wo; dst = wob; i = (b - 4800) * 256 + t; }  // 147456 f4
  const float4 v = ((const float4*)src)[i];
  ushort4 o;
  o.x = bf16bits(v.x); o.y = bf16bits(v.y); o.z = bf16bits(v.z); o.w = bf16bits(v.w);
  ((ushort4*)dst)[i] = o;
}

// m97-style staging of a 128x64 bf16 tile: wave w stages rows w*32..+31 via 4
// async16 (each = 8 rows x 64 cols contiguous LDS). LDS unpadded [row][64].
#define GEMM_STAGE(Ms, Mp, MK)                                                 \
  do {                                                                         \
    _Pragma("unroll")                                                          \
    for (int i_ = 0; i_ < 4; i_++)                                             \
      async16(&Ms[(wave * 32 + i_ * 8) * 64],                                  \
              Mp + (size_t)(wave * 32 + i_ * 8 + lrow) * (MK) + lcol);         \
  } while (0)

// ---- GEMM1: qkv = x @ w_qkv^T.  Q cols pre-scaled by log2e/8 -> qk[n][1536];
//      V cols -> vtg[h*64+d][n] (fused transpose).
__global__ void __launch_bounds__(256) gemm_qkv(const ushort* __restrict__ A,
                                                const ushort* __restrict__ B,
                                                ushort* __restrict__ qkb,
                                                ushort* __restrict__ vtg) {
  __shared__ __align__(16) ushort As[128 * 64];
  __shared__ __align__(16) ushort Bs[128 * 64];
  const int tid = threadIdx.x;
  const int wave = tid >> 6, lane = tid & 63, quad = lane >> 4, l16 = lane & 15;
  const int wm = wave & 1, wn = wave >> 1;
  const int lrow = lane >> 3, lcol = (lane & 7) * 8;
  const int m0 = blockIdx.y * 128, n0 = blockIdx.x * 128;
  const int K = DMODEL;

  f32x4 acc[4][4] = {};
  const ushort* Ap = A + (size_t)m0 * K;
  const ushort* Bp = B + (size_t)n0 * K;

  for (int k0 = 0; k0 < K; k0 += 64) {
    GEMM_STAGE(As, Ap + k0, K);
    GEMM_STAGE(Bs, Bp + k0, K);
    __syncthreads();   // drains vmcnt -> staged data visible
#pragma unroll
    for (int ks = 0; ks < 2; ks++) {
      short8 af[4], bf[4];
#pragma unroll
      for (int i = 0; i < 4; i++) {
        af[i] = *(const short8*)&As[(wm * 64 + i * 16 + l16) * 64 + ks * 32 + quad * 8];
        bf[i] = *(const short8*)&Bs[(wn * 64 + i * 16 + l16) * 64 + ks * 32 + quad * 8];
      }
#pragma unroll
      for (int mi = 0; mi < 4; mi++)
#pragma unroll
        for (int ni = 0; ni < 4; ni++)
          acc[mi][ni] = __builtin_amdgcn_mfma_f32_16x16x32_bf16(af[mi], bf[ni], acc[mi][ni], 0, 0, 0);
    }
    __syncthreads();
  }

  if (n0 < QK_LD) {
    // Q/K epilogue: qk[row][col].  Q (col<768) pre-scaled so attn exp2 needs no mul.
    const float qsc = (n0 + 128 <= 768) ? 0.18033688011112042f : 1.0f;  // log2(e)/8
#pragma unroll
    for (int mi = 0; mi < 4; mi++)
#pragma unroll
      for (int ni = 0; ni < 4; ni++) {
        const int col = n0 + wn * 64 + ni * 16 + l16;
#pragma unroll
        for (int rr = 0; rr < 4; rr++) {
          const int row = m0 + wm * 64 + mi * 16 + quad * 4 + rr;
          qkb[(size_t)row * QK_LD + col] = bf16bits(acc[mi][ni][rr] * qsc);
        }
      }
  } else {
    // V epilogue: vtg[col-1536][row], 4 consecutive rows packed per lane.
#pragma unroll
    for (int mi = 0; mi < 4; mi++)
#pragma unroll
      for (int ni = 0; ni < 4; ni++) {
        const int col = n0 + wn * 64 + ni * 16 + l16 - QK_LD;   // = h*64+d
        const int rowb = m0 + wm * 64 + mi * 16 + quad * 4;
        const unsigned u0 = (unsigned)bf16bits(acc[mi][ni][0]) |
                            ((unsigned)bf16bits(acc[mi][ni][1]) << 16);
        const unsigned u1 = (unsigned)bf16bits(acc[mi][ni][2]) |
                            ((unsigned)bf16bits(acc[mi][ni][3]) << 16);
        *(uint2*)&vtg[(size_t)col * N_TOK + rowb] = make_uint2(u0, u1);
      }
  }
}

// ---- GEMM2: out = aout @ w_out^T + bias (fp32 out) ----
__global__ void __launch_bounds__(256) gemm_out(const ushort* __restrict__ A,
                                                const ushort* __restrict__ B,
                                                float* __restrict__ Cf,
                                                const float* __restrict__ bias) {
  __shared__ __align__(16) ushort As[128 * 64];
  __shared__ __align__(16) ushort Bs[128 * 64];
  const int tid = threadIdx.x;
  const int wave = tid >> 6, lane = tid & 63, quad = lane >> 4, l16 = lane & 15;
  const int wm = wave & 1, wn = wave >> 1;
  const int lrow = lane >> 3, lcol = (lane & 7) * 8;
  const int m0 = blockIdx.y * 128, n0 = blockIdx.x * 128;
  const int K = DMODEL, Nn = DMODEL;

  f32x4 acc[4][4] = {};
  const ushort* Ap = A + (size_t)m0 * K;
  const ushort* Bp = B + (size_t)n0 * K;

  for (int k0 = 0; k0 < K; k0 += 64) {
    GEMM_STAGE(As, Ap + k0, K);
    GEMM_STAGE(Bs, Bp + k0, K);
    __syncthreads();
#pragma unroll
    for (int ks = 0; ks < 2; ks++) {
      short8 af[4], bf[4];
#pragma unroll
      for (int i = 0; i < 4; i++) {
        af[i] = *(const short8*)&As[(wm * 64 + i * 16 + l16) * 64 + ks * 32 + quad * 8];
        bf[i] = *(const short8*)&Bs[(wn * 64 + i * 16 + l16) * 64 + ks * 32 + quad * 8];
      }
#pragma unroll
      for (int mi = 0; mi < 4; mi++)
#pragma unroll
        for (int ni = 0; ni < 4; ni++)
          acc[mi][ni] = __builtin_amdgcn_mfma_f32_16x16x32_bf16(af[mi], bf[ni], acc[mi][ni], 0, 0, 0);
    }
    __syncthreads();
  }

#pragma unroll
  for (int mi = 0; mi < 4; mi++)
#pragma unroll
    for (int ni = 0; ni < 4; ni++) {
      const int col = n0 + wn * 64 + ni * 16 + l16;
#pragma unroll
      for (int rr = 0; rr < 4; rr++) {
        const int row = m0 + wm * 64 + mi * 16 + quad * 4 + rr;
        Cf[(size_t)row * Nn + col] = acc[mi][ni][rr] + bias[col];
      }
    }
}

// ---- Flash attention: q=256/block, transposed-S, static max, KV-split-S ----
// Grid 192*S (1D). XCD swizzle: s8=b%8, slice=s8+8*(j%nsl8), qb=j/nsl8;
// h=slice%12, sp=slice/12. ntiles = 64/S covers ALL KV tiles.
// __launch_bounds__(256,2): the wave needs ~205 live VGPRs; bound 3 spills.
#define BARRIER_LGKM() asm volatile("s_waitcnt lgkmcnt(0)\n\ts_barrier" ::: "memory")

#define ATTN_LOAD(tile, K0, K1, V0, V1)                                        \
  do {                                                                         \
    const int kv0_ = (tile) * 64;                                              \
    K0 = *(const uint4*)(kbase + (size_t)(kv0_ + sr) * QK_LD);                 \
    K1 = *(const uint4*)(kbase + (size_t)(kv0_ + sr + 32) * QK_LD);            \
    V0 = *(const uint4*)(vbase + (size_t)sr * N_TOK + kv0_ + sc);              \
    V1 = *(const uint4*)(vbase + (size_t)(sr + 32) * N_TOK + kv0_ + sc);       \
  } while (0)

#define ATTN_SINK(buf, K0, K1, V0, V1)                                         \
  do {                                                                         \
    *(uint4*)&Ks[buf][sg * KSTR + sc] = K0;                                    \
    *(uint4*)&Ks[buf][(sg + 32) * KSTR + sc] = K1;                             \
    *(uint4*)&Vs[buf][sr * KSTR + sc] = V0;                                    \
    *(uint4*)&Vs[buf][(sr + 32) * KSTR + sc] = V1;                             \
  } while (0)

#define ATTN_TILE(KbP, VbP)                                                    \
  do {                                                                         \
    const ushort* Kb_ = (KbP);                                                 \
    const ushort* Vb_ = (VbP);                                                 \
    f32x4 st[4][4];                                                            \
    _Pragma("unroll")                                                          \
    for (int nt = 0; nt < 4; nt++) {                                           \
      const short8 kf0 = *(const short8*)&Kb_[(nt * 16 + l16) * KSTR + quad * 8];      \
      const short8 kf1 = *(const short8*)&Kb_[(nt * 16 + l16) * KSTR + 32 + quad * 8]; \
      _Pragma("unroll")                                                        \
      for (int s = 0; s < 4; s++) {                                            \
        f32x4 a = {};                                                          \
        a = __builtin_amdgcn_mfma_f32_16x16x32_bf16(kf0, qf[s][0], a, 0, 0, 0);\
        a = __builtin_amdgcn_mfma_f32_16x16x32_bf16(kf1, qf[s][1], a, 0, 0, 0);\
        st[s][nt] = a;                                                         \
      }                                                                        \
    }                                                                          \
    unsigned pk[4][4][2];                                                      \
    _Pragma("unroll")                                                          \
    for (int s = 0; s < 4; s++)                                                \
      _Pragma("unroll")                                                        \
      for (int nt = 0; nt < 4; nt++) {                                         \
        const unsigned u0 = __float_as_uint(EXP2F(st[s][nt][0]));              \
        const unsigned u1 = __float_as_uint(EXP2F(st[s][nt][1]));              \
        const unsigned u2 = __float_as_uint(EXP2F(st[s][nt][2]));              \
        const unsigned u3 = __float_as_uint(EXP2F(st[s][nt][3]));              \
        pk[s][nt][0] = PACK2BF(u1, u0);                                        \
        pk[s][nt][1] = PACK2BF(u3, u2);                                        \
      }                                                                        \
    _Pragma("unroll")                                                          \
    for (int ks = 0; ks < 2; ks++) {                                           \
      short8 pf[4];                                                            \
      _Pragma("unroll")                                                        \
      for (int s = 0; s < 4; s++) {                                            \
        union { unsigned u[4]; short8 v; } t;                                  \
        t.u[0] = pk[s][2 * ks][0];                                             \
        t.u[1] = pk[s][2 * ks][1];                                             \
        t.u[2] = pk[s][2 * ks + 1][0];                                         \
        t.u[3] = pk[s][2 * ks + 1][1];                                         \
        pf[s] = t.v;                                                           \
        lacc[s] = __builtin_amdgcn_mfma_f32_16x16x32_bf16(pf[s], onesf, lacc[s], 0, 0, 0); \
      }                                                                        \
      _Pragma("unroll")                                                        \
      for (int dt = 0; dt < 4; dt++) {                                         \
        const short8 vf = *(const short8*)&Vb_[(dt * 16 + l16) * KSTR + ks * 32 + quad * 8]; \
        _Pragma("unroll")                                                      \
        for (int s = 0; s < 4; s++)                                            \
          o[s][dt] = __builtin_amdgcn_mfma_f32_16x16x32_bf16(pf[s], vf, o[s][dt], 0, 0, 0); \
      }                                                                        \
    }                                                                          \
  } while (0)

__global__ void __launch_bounds__(256, 2) attn_flash(const ushort* __restrict__ qk,
                                                     const ushort* __restrict__ vtg,
                                                     ushort* __restrict__ pob,
                                                     float* __restrict__ pl,
                                                     int ntiles, int nsl8) {
  __shared__ __align__(16) ushort Ks[2][64 * KSTR];
  __shared__ __align__(16) ushort Vs[2][64 * KSTR];

  const int b = blockIdx.x;
  const int s8 = b & 7;               // presumed XCD (round-robin dispatch)
  const int j = b >> 3;
  const int slice = s8 + 8 * (j % nsl8);   // 0..12*S-1, pinned to XCD s8
  const int qb = j / nsl8;                 // 0..15
  const int h = slice % NHEAD;
  const int sp = slice / NHEAD;            // 0..S-1

  const int tid = threadIdx.x;
  const int wave = tid >> 6, lane = tid & 63, quad = lane >> 4, l16 = lane & 15;
  const int q0 = qb * 256;

  // Q fragments (B-operand: q = l16 within strip, k = quad*8+j). Pre-scaled by log2e/8.
  short8 qf[4][2];
#pragma unroll
  for (int s = 0; s < 4; s++) {
    const ushort* qp = qk + (size_t)(q0 + wave * 64 + s * 16 + l16) * QK_LD + h * 64 + quad * 8;
    qf[s][0] = *(const short8*)qp;
    qf[s][1] = *(const short8*)(qp + 32);
  }

  const int sr = tid >> 3, sc = (tid & 7) * 8;
  // sigma row permutation for K staging: g -> (2*(g>>5)+((g>>2)&1))*16+((g>>3)&3)*4+(g&3)
  const int sg = ((sr >> 2) & 1) * 16 + ((sr >> 3) & 3) * 4 + (sr & 3);

  const ushort* kbase = qk + 768 + h * 64 + sc;
  const ushort* vbase = vtg + (size_t)(h * 64) * N_TOK;
  const int kt0 = sp * ntiles;

  f32x4 o[4][4] = {};
  f32x4 lacc[4] = {};
  const short8 onesf = { (short)0x3F80, (short)0x3F80, (short)0x3F80, (short)0x3F80,
                         (short)0x3F80, (short)0x3F80, (short)0x3F80, (short)0x3F80 };

  uint4 ka0, ka1, va0, va1;   // slot A (odd tiles)
  uint4 kb0, kb1, vb0, vb1;   // slot B (even tiles >= 2)

  // prologue: tile kt0 direct to LDS buf0; prefetch tile kt0+1 into A
  ATTN_LOAD(kt0, ka0, ka1, va0, va1);
  ATTN_SINK(0, ka0, ka1, va0, va1);
  ATTN_LOAD(kt0 + 1, ka0, ka1, va0, va1);

  for (int kt = 0; kt < ntiles; kt += 2) {
    // ---- even tile kt: compute LDS0; sink A(tile kt+1)->LDS1; prefetch B(tile kt+2)
    BARRIER_LGKM();
    if (kt + 2 < ntiles) ATTN_LOAD(kt0 + kt + 2, kb0, kb1, vb0, vb1);
    ATTN_TILE(Ks[0], Vs[0]);
    ATTN_SINK(1, ka0, ka1, va0, va1);
    // ---- odd tile kt+1: compute LDS1; sink B(tile kt+2)->LDS0; prefetch A(tile kt+3)
    BARRIER_LGKM();
    if (kt + 3 < ntiles) ATTN_LOAD(kt0 + kt + 3, ka0, ka1, va0, va1);
    ATTN_TILE(Ks[1], Vs[1]);
    if (kt + 2 < ntiles) ATTN_SINK(0, kb0, kb1, vb0, vb1);
  }

  // ---- epilogue: o and lacc share row indexing (q = s*16 + quad*4 + rr) ----
#pragma unroll
  for (int s = 0; s < 4; s++) {
#pragma unroll
    for (int rr = 0; rr < 4; rr++) {
      const float l = lacc[s][rr];
      const float inv = 1.f / l;
      const int row = q0 + wave * 64 + s * 16 + quad * 4 + rr;
      if (l16 == 0)
        pl[(size_t)(sp * NHEAD + h) * N_TOK + row] = l;
#pragma unroll
      for (int dt = 0; dt < 4; dt++)
        pob[((size_t)sp * N_TOK + row) * DMODEL + h * 64 + dt * 16 + l16] =
            bf16bits(o[s][dt][rr] * inv);
    }
  }
}

// ---- combine S split partials: aout = sum(l_s * o_s) / sum(l_s), bf16 ----
// grid: 786432 ushort4-groups / 256 = 3072 blocks
__global__ void __launch_bounds__(256) combine(const ushort* __restrict__ pob,
                                               const float* __restrict__ pl,
                                               ushort* __restrict__ aout, int S) {
  const int i = blockIdx.x * 256 + threadIdx.x;   // ushort4 index
  const int row = i / (DMODEL / 4);
  const int hd = (i % (DMODEL / 4)) * 4;
  const int h = hd >> 6;
  float lt = 0.f, a0 = 0.f, a1 = 0.f, a2 = 0.f, a3 = 0.f;
  for (int s = 0; s < S; s++) {
    const float l = pl[((size_t)s * NHEAD + h) * N_TOK + row];
    const ushort4 a = *(const ushort4*)&pob[((size_t)s * N_TOK + row) * DMODEL + hd];
    lt += l;
    a0 += l * bf2f(a.x); a1 += l * bf2f(a.y); a2 += l * bf2f(a.z); a3 += l * bf2f(a.w);
  }
  const float inv = 1.f / lt;
  ushort4 r;
  r.x = bf16bits(a0 * inv); r.y = bf16bits(a1 * inv);
  r.z = bf16bits(a2 * inv); r.w = bf16bits(a3 * inv);
  *(ushort4*)&aout[(size_t)row * DMODEL + hd] = r;
}

extern "C" void kernel_launch(void* const* d_in, const int* in_sizes, int n_in,
                              void* d_out, int out_size, void* d_ws, size_t ws_size,
                              hipStream_t stream) {
  const float* x     = (const float*)d_in[0];
  const float* w_qkv = (const float*)d_in[1];
  const float* w_out = (const float*)d_in[2];
  const float* b_out = (const float*)d_in[3];
  float* out = (float*)d_out;

  // ws layout (runtime split count S): pob at 0 (S*6.29 MB; xb/wqkvb alias its
  // head, both dead before attn); then qkb, vtg, woutb, pl. aout aliases qkb.
  const size_t PO_UNIT = 6291456UL;   // 4096*768*2
  const int S = (ws_size >= 4 * PO_UNIT + 20840448UL) ? 4 : 2;
  char* ws = (char*)d_ws;
  ushort* pob   = (ushort*)ws;
  ushort* xb    = (ushort*)ws;                          // [0, 6.29M) dead after gemm1
  ushort* wqkvb = (ushort*)(ws + 6291456UL);            // [6.29M, 9.83M) dead after gemm1
  ushort* qkb   = (ushort*)(ws + (size_t)S * PO_UNIT);
  ushort* vtg   = (ushort*)((char*)qkb + 12582912UL);
  ushort* woutb = (ushort*)((char*)vtg + 6291456UL);
  float*  pl    = (float*)((char*)woutb + 1179648UL);
  ushort* aoutb = qkb;                                  // qkb dead after attn

  // 1) converts (one kernel, 3 ranges: 3072 + 1728 + 576 blocks)
  cvt3<<<5376, 256, 0, stream>>>(x, w_qkv, w_out, xb, wqkvb, woutb);

  // 2) qkv GEMM (global_load_lds staging) with fused V-transpose epilogue + Q pre-scale
  gemm_qkv<<<dim3(18, 32), 256, 0, stream>>>(xb, wqkvb, qkb, vtg);

  // 3) flash attention (q=256/block, KV-split-S over ALL 64 tiles: ntiles = 64/S)
  attn_flash<<<192 * S, 256, 0, stream>>>(qkb, vtg, pob, pl, 64 / S, (12 * S) / 8);

  // 4) combine partials -> aout bf16
  combine<<<3072, 256, 0, stream>>>(pob, pl, aoutb, S);

  // 5) out = aout @ w_out^T + b_out (global_load_lds staging)
  gemm_out<<<dim3(6, 32), 256, 0, stream>>>(aoutb, woutb, out, b_out);
}